// Round 1
// 369.725 us; speedup vs baseline: 1.0767x; 1.0767x over previous
//
#include <hip/hip_runtime.h>

// ANI symmetry functions: radial scatter-add AEV + angular feature map.
// Round 4 (fusion round):
//  - Rounds 1-3 established radial is ATOMIC-RATE-bound: 3.2M u64 atomics at
//    the flat ~22-23 G/s device RMW rate = 138 us, with VALUBusy 2.3% and
//    HBM at 10% of peak. Atomic count is already minimal (one packed u64 per
//    row-update via 3-shell window + overlapping groups).
//  - Angular is streaming-write-bound (205 MB out) and uses NO atomics.
//    The two kernels stress disjoint pipes but ran sequentially.
//  - This round: GRID-PARTITIONED FUSION. One kernel, 12500 blocks; even
//    blocks take an angular tile, odd blocks a radial tile (both need
//    exactly 6250), so both populations are co-resident on every CU and
//    the dispatch costs ~max(atomic floor, angular) instead of the sum.
//    Combined HBM (95+243=340 MB -> ~54 us) stays under the 138 us atomic
//    floor, so BW does not become the limit.
//  - Cost: angular's 33.8 KB static LDS is allocated for radial blocks too
//    (4 blocks/CU, ~50% occupancy). Radial is rate-bound, not latency-bound
//    (flat from 71% occupancy down in rounds 1-2), so this is harmless.

#define N_ATOMS 50000
#define N_ELEM 7
#define RADIAL_DIV 8
#define NROWS (N_ATOMS * N_ELEM)

constexpr float RADIAL_CUTOFF = 5.1f;
constexpr float ANGULAR_CUTOFF = 3.5f;
constexpr float ETA_R = 19.7f;
constexpr float ETA_A = 12.5f;
constexpr float ZETA = 14.1f;
constexpr float PI_F = 3.14159265358979323846f;
constexpr float FP_SCALE = 4096.0f;          // 2^12 fixed-point scale
constexpr float FP_INV = 1.0f / 4096.0f;
constexpr float SHELL_STEP = 0.5375f;        // (5.1-0.8)/8
constexpr float INV_SHELL_STEP = 1.0f / 0.5375f;

// ShfZ[j] = (j+0.5)*pi/4 ; precomputed cos/sin:
__device__ __constant__ float CSZ[4] = { 0.9238795325f,  0.3826834324f, -0.3826834324f, -0.9238795325f };
__device__ __constant__ float SNZ[4] = { 0.3826834324f,  0.9238795325f,  0.9238795325f,  0.3826834324f };

#define BLK 256

// acc layout: [NROWS][3] u64. Group g holds shells 2g..2g+3 as 4 x u16 lanes.
// Any 3-shell window (eta_R=19.7 => only 3 shells non-negligible) fits in
// ONE group => 1 u64 atomic per row-update, 2 per pair.
__global__ __launch_bounds__(BLK) void fused_kernel(
        const float* __restrict__ r_ij,        // [P]
        const int* __restrict__ pair_idx,      // [2, P]
        const int* __restrict__ Z,             // [N_ATOMS]
        unsigned long long* __restrict__ acc,  // [NROWS, 3]
        int P,
        const float* __restrict__ vec12,       // [2, T, 3]
        float* __restrict__ ang,               // [T, 32]
        int T,
        int nRad, int nAng) {
    __shared__ float sm[BLK * 33];             // 33-stride pad kills bank conflicts
    int bid = blockIdx.x;
    int tid = threadIdx.x;

    // Interleaved block->role mapping: while both roles have tiles left,
    // even blocks are angular, odd blocks are radial. Leftover blocks (if
    // counts differ) go to the majority role.
    int paired = min(nRad, nAng);
    bool isAng;
    int id;
    if (bid < 2 * paired) {
        isAng = ((bid & 1) == 0);
        id = bid >> 1;
    } else {
        id = bid - paired;                     // = paired + (bid - 2*paired)
        isAng = (nAng > nRad);
    }

    if (!isAng) {
        // ---------------- radial tile ----------------
        int t = id * BLK + tid;
        if (t >= P) return;
        float d = r_ij[t];
        float fc = (d <= RADIAL_CUTOFF)
                       ? (0.5f * __cosf(PI_F * d * (1.0f / RADIAL_CUTOFF)) + 0.5f)
                       : 0.0f;

        // nearest-shell window [a, a+2], a in [0,5]
        float x = (d - 0.8f) * INV_SHELL_STEP;
        int k0 = (int)(x + 0.5f);
        k0 = min(max(k0, 1), 6);
        int a = k0 - 1;
        int g = a >> 1;                        // owning group: shells 2g..2g+3 cover a..a+2
        int sh = (a & 1) << 4;                 // bit offset of lane (a-2g)

        unsigned long long w = 0ull;
        #pragma unroll
        for (int j = 0; j < 3; j++) {
            float diff = d - (0.8f + SHELL_STEP * (float)(a + j));
            float gv = 0.25f * __expf(-ETA_R * diff * diff) * fc;   // [0, 0.25]
            unsigned int q = (unsigned int)(gv * FP_SCALE + 0.5f);
            w |= (unsigned long long)q << (16 * j);
        }
        w <<= sh;
        if (w == 0ull) return;                 // d near cutoff: all three quantize to 0

        int i0 = pair_idx[t];
        int i1 = pair_idx[P + t];
        int s0 = Z[i0];
        int s1 = Z[i1];
        atomicAdd(acc + ((size_t)i0 * N_ELEM + s1) * 3 + g, w);   // index12[0] uses partner species
        atomicAdd(acc + ((size_t)i1 * N_ELEM + s0) * 3 + g, w);
        return;
    }

    // ---------------- angular tile ----------------
    int t = id * BLK + tid;
    float vals[32];
    if (t < T) {
        const float* v1 = vec12 + 3ull * (size_t)t;
        const float* v2 = vec12 + 3ull * (size_t)T + 3ull * (size_t)t;
        float x1 = v1[0], y1 = v1[1], z1 = v1[2];
        float x2 = v2[0], y2 = v2[1], z2 = v2[2];

        float d1 = sqrtf(x1 * x1 + y1 * y1 + z1 * z1);
        float d2 = sqrtf(x2 * x2 + y2 * y2 + z2 * z2);
        float dot = x1 * x2 + y1 * y2 + z1 * z2;
        float cost = 0.95f * dot / (d1 * d2);                  // |cost| <= 0.95
        float sint = sqrtf(fmaxf(0.0f, 1.0f - cost * cost));   // theta in [0,pi] -> sin >= 0

        float fc1 = (d1 <= ANGULAR_CUTOFF) ? (0.5f * __cosf(PI_F * d1 * (1.0f / ANGULAR_CUTOFF)) + 0.5f) : 0.0f;
        float fc2 = (d2 <= ANGULAR_CUTOFF) ? (0.5f * __cosf(PI_F * d2 * (1.0f / ANGULAR_CUTOFF)) + 0.5f) : 0.0f;
        float fc = fc1 * fc2;

        float davg = 0.5f * (d1 + d2);
        float frad[8];
        #pragma unroll
        for (int k = 0; k < 8; k++) {
            float diff = davg - (0.8f + 0.3375f * (float)k);
            frad[k] = __expf(-ETA_A * diff * diff);
        }
        #pragma unroll
        for (int j = 0; j < 4; j++) {
            // cos(theta - ShfZ[j]) = cost*cos(s) + sint*sin(s)
            float c = 0.5f * (1.0f + cost * CSZ[j] + sint * SNZ[j]);   // in [0.025, 1]
            float base = 2.0f * __powf(c, ZETA) * fc;
            #pragma unroll
            for (int k = 0; k < 8; k++) vals[j * 8 + k] = base * frad[k];
        }
    } else {
        #pragma unroll
        for (int k = 0; k < 32; k++) vals[k] = 0.0f;
    }

    #pragma unroll
    for (int k = 0; k < 32; k++) sm[tid * 33 + k] = vals[k];
    __syncthreads();

    // Coalesced write of the block's [BLK,32] region: 8 float4 per thread.
    size_t base = (size_t)id * BLK * 32;
    size_t lim = (size_t)T * 32;
    #pragma unroll
    for (int it = 0; it < 8; it++) {
        int f = it * BLK + tid;                  // float4 index within block
        int row = f >> 3;                        // f*4/32
        int col = (f & 7) * 4;
        float4 o;
        o.x = sm[row * 33 + col + 0];
        o.y = sm[row * 33 + col + 1];
        o.z = sm[row * 33 + col + 2];
        o.w = sm[row * 33 + col + 3];
        size_t gidx = base + (size_t)f * 4;
        if (gidx < lim) reinterpret_cast<float4*>(ang)[gidx >> 2] = o;
    }
}

// Reconstruct f32 row from 3 overlapping u64 groups.
__global__ void convert_kernel(const unsigned long long* __restrict__ acc,
                               float* __restrict__ aev, int nrows) {
    int r = blockIdx.x * blockDim.x + threadIdx.x;
    if (r >= nrows) return;
    unsigned long long g0 = acc[3 * (size_t)r + 0];
    unsigned long long g1 = acc[3 * (size_t)r + 1];
    unsigned long long g2 = acc[3 * (size_t)r + 2];
    unsigned int l0[4], l1[4], l2[4];
    #pragma unroll
    for (int j = 0; j < 4; j++) {
        l0[j] = (unsigned int)(g0 >> (16 * j)) & 0xFFFFu;
        l1[j] = (unsigned int)(g1 >> (16 * j)) & 0xFFFFu;
        l2[j] = (unsigned int)(g2 >> (16 * j)) & 0xFFFFu;
    }
    float4 oa, ob;
    oa.x = (float)(l0[0])         * FP_INV;           // shell 0
    oa.y = (float)(l0[1])         * FP_INV;           // shell 1
    oa.z = (float)(l0[2] + l1[0]) * FP_INV;           // shell 2
    oa.w = (float)(l0[3] + l1[1]) * FP_INV;           // shell 3
    ob.x = (float)(l1[2] + l2[0]) * FP_INV;           // shell 4
    ob.y = (float)(l1[3] + l2[1]) * FP_INV;           // shell 5
    ob.z = (float)(l2[2])         * FP_INV;           // shell 6
    ob.w = (float)(l2[3])         * FP_INV;           // shell 7
    float4* o = reinterpret_cast<float4*>(aev + 8ull * (size_t)r);
    o[0] = oa;
    o[1] = ob;
}

extern "C" void kernel_launch(void* const* d_in, const int* in_sizes, int n_in,
                              void* d_out, int out_size, void* d_ws, size_t ws_size,
                              hipStream_t stream) {
    const float* r_ij     = (const float*)d_in[0];
    const int*   pair_idx = (const int*)d_in[1];
    const int*   Z        = (const int*)d_in[2];
    const float* vec12    = (const float*)d_in[3];

    const int P = in_sizes[0];           // 1,600,000 pairs
    const int T = in_sizes[3] / 6;       // 1,600,000 triplets

    float* aev = (float*)d_out;                                  // [NROWS, 8]
    float* ang = aev + (size_t)NROWS * RADIAL_DIV;               // [T, 32]

    unsigned long long* acc = (unsigned long long*)d_ws;         // [NROWS, 3] u64 = 8.4 MB
    hipMemsetAsync(acc, 0, (size_t)NROWS * 3 * sizeof(unsigned long long), stream);

    const int nRad = (P + BLK - 1) / BLK;
    const int nAng = (T + BLK - 1) / BLK;
    fused_kernel<<<dim3(nRad + nAng), dim3(BLK), 0, stream>>>(
        r_ij, pair_idx, Z, acc, P, vec12, ang, T, nRad, nAng);
    convert_kernel<<<dim3((NROWS + 255) / 256), dim3(256), 0, stream>>>(acc, aev, NROWS);
}